// Round 5
// baseline (71.355 us; speedup 1.0000x reference)
//
#include <hip/hip_runtime.h>

// Path signature, depth 4, C=8, L=256, N=256.
// One block per sample, 256 threads. Thread tid owns:
//   i = tid>>5, j = (tid>>2)&7, k0 = 2*(tid&3)
//   level-4 elements (i,j,k,l) for k in {k0,k0+1}, l in 0..7  -> acc[16]
//   level-3 elements (i,j,k0), (i,j,k0+1)                     -> s3a, s3b
//   private replicas of level-2 (i,j) and level-1 (i)         -> s2, s1
// Chen's relation factored so each level-4 element costs 1 FMA per step.
// No barriers / shared signature state in the recursion loop.

constexpr int N_SAMP = 256;
constexpr int L_LEN = 256;
constexpr int C_DIM = 8;
constexpr int OUT_PER = 8 + 64 + 512 + 4096; // 4680

__global__ __launch_bounds__(256) void sig_kernel(const float* __restrict__ path,
                                                  float* __restrict__ out) {
    __shared__ float dx[(L_LEN - 1) * C_DIM]; // 255*8 floats = 8160 B

    const int n = blockIdx.x;
    const int tid = threadIdx.x;

    // ---- stage increments into LDS ----
    const float* p = path + (size_t)n * L_LEN * C_DIM;
    if (tid < L_LEN - 1) {
        float4 a0 = *(const float4*)(p + tid * C_DIM);
        float4 a1 = *(const float4*)(p + tid * C_DIM + 4);
        float4 b0 = *(const float4*)(p + (tid + 1) * C_DIM);
        float4 b1 = *(const float4*)(p + (tid + 1) * C_DIM + 4);
        float4 d0 = make_float4(b0.x - a0.x, b0.y - a0.y, b0.z - a0.z, b0.w - a0.w);
        float4 d1 = make_float4(b1.x - a1.x, b1.y - a1.y, b1.z - a1.z, b1.w - a1.w);
        *(float4*)(&dx[tid * C_DIM]) = d0;
        *(float4*)(&dx[tid * C_DIM + 4]) = d1;
    }
    __syncthreads();

    const int i = tid >> 5;
    const int j = (tid >> 2) & 7;
    const int k0 = (tid & 3) * 2;

    float acc[16];
#pragma unroll
    for (int m = 0; m < 16; ++m) acc[m] = 0.f;
    float s3a = 0.f, s3b = 0.f, s2 = 0.f, s1 = 0.f;

    constexpr float THIRD = 1.f / 3.f;

#pragma unroll 5
    for (int t = 0; t < L_LEN - 1; ++t) {
        const float* v = &dx[t * C_DIM];
        float vv[8];
#pragma unroll
        for (int c = 0; c < 8; ++c) vv[c] = v[c]; // 2x ds_read_b128 (broadcast)
        float vi = v[i];
        float vj = v[j];
        float2 vk = *(const float2*)(v + k0); // ds_read_b64
        float vk0 = vk.x, vk1 = vk.y;

        // factored Chen coefficients (all use OLD s1,s2,s3)
        float c4 = fmaf(vj * THIRD, fmaf(0.25f, vi, s1), s2);
        float c3 = fmaf(vj * 0.5f, fmaf(THIRD, vi, s1), s2);
        float f0 = fmaf(c4, 0.5f * vk0, s3a);
        float f1 = fmaf(c4, 0.5f * vk1, s3b);

        // level 4: one FMA per owned element
#pragma unroll
        for (int l = 0; l < 8; ++l) {
            acc[l] = fmaf(f0, vv[l], acc[l]);
            acc[8 + l] = fmaf(f1, vv[l], acc[8 + l]);
        }
        // level 3
        s3a = fmaf(c3, vk0, s3a);
        s3b = fmaf(c3, vk1, s3b);
        // level 2
        s2 = fmaf(fmaf(0.5f, vi, s1), vj, s2);
        // level 1
        s1 += vi;
    }

    // ---- write out: [s1(8), s2(64), s3(512), s4(4096)] ----
    float* o = out + (size_t)n * OUT_PER;
    if ((tid & 31) == 0) o[i] = s1;
    if ((tid & 3) == 0) o[8 + i * 8 + j] = s2;
    *(float2*)(o + 72 + tid * 2) = make_float2(s3a, s3b);
    float4* o4 = (float4*)(o + 584 + tid * 16);
    o4[0] = make_float4(acc[0], acc[1], acc[2], acc[3]);
    o4[1] = make_float4(acc[4], acc[5], acc[6], acc[7]);
    o4[2] = make_float4(acc[8], acc[9], acc[10], acc[11]);
    o4[3] = make_float4(acc[12], acc[13], acc[14], acc[15]);
}

extern "C" void kernel_launch(void* const* d_in, const int* in_sizes, int n_in,
                              void* d_out, int out_size, void* d_ws, size_t ws_size,
                              hipStream_t stream) {
    const float* path = (const float*)d_in[0];
    float* out = (float*)d_out;
    sig_kernel<<<N_SAMP, 256, 0, stream>>>(path, out);
}

// Round 7
// 67.806 us; speedup vs baseline: 1.0523x; 1.0523x over previous
//
#include <hip/hip_runtime.h>

// Path signature, depth 4, C=8, L=256, N=256 — time-segmented version.
// One block (1024 thr = 16 waves = 4 waves/SIMD) per sample.
// 4 groups of 256 threads each run the factored Chen recursion over a
// 64/64/64/63-increment segment (no barriers, no shared sig state), then the
// 4 segment signatures are combined in LDS via 3 Chen products.
// Per-CU VALU issue count is unchanged vs the 1-wave version; the 4x wave
// count hides the ds_read (~120cy) and FMA dependency latency that made the
// single-wave version stall-bound.

constexpr int N_SAMP = 256;
constexpr int L_LEN = 256;
constexpr int C_DIM = 8;
constexpr int OUT_PER = 8 + 64 + 512 + 4096; // 4680
constexpr int NSEG = 4;
constexpr int SIG_STRIDE = 4688; // 4680 padded

__global__ __launch_bounds__(1024) void sig_kernel(const float* __restrict__ path,
                                                   float* __restrict__ out) {
    __shared__ float dx[(L_LEN - 1) * C_DIM];   // 2040 floats
    __shared__ float sig[NSEG][SIG_STRIDE];     // 4*4688 floats = 75 KB

    const int n = blockIdx.x;
    const int tid = threadIdx.x;

    // ---- stage increments into LDS (1020 float2's) ----
    const float* p = path + (size_t)n * L_LEN * C_DIM;
    if (tid < 1020) {
        float2 a = *(const float2*)(p + tid * 2);
        float2 b = *(const float2*)(p + tid * 2 + C_DIM);
        *(float2*)(&dx[tid * 2]) = make_float2(b.x - a.x, b.y - a.y);
    }
    __syncthreads();

    // ---- phase 1: per-segment recursion ----
    const int seg = tid >> 8;      // 0..3
    const int r = tid & 255;
    const int i = r >> 5;
    const int j = (r >> 2) & 7;
    const int k0 = (r & 3) * 2;

    const int t0 = seg * 64;
    const int tcnt = (seg == 3) ? 63 : 64;   // wave-uniform

    float acc[16];
#pragma unroll
    for (int m = 0; m < 16; ++m) acc[m] = 0.f;
    float s3a = 0.f, s3b = 0.f, s2 = 0.f, s1 = 0.f;

    constexpr float THIRD = 1.f / 3.f;

#pragma unroll 4
    for (int t = 0; t < tcnt; ++t) {
        const float* v = &dx[(t0 + t) * C_DIM];
        float vv[8];
#pragma unroll
        for (int c = 0; c < 8; ++c) vv[c] = v[c]; // broadcast ds_read_b128 x2
        float vi = v[i];
        float vj = v[j];
        float2 vk = *(const float2*)(v + k0);
        float vk0 = vk.x, vk1 = vk.y;

        float c4 = fmaf(vj * THIRD, fmaf(0.25f, vi, s1), s2);
        float c3 = fmaf(vj * 0.5f, fmaf(THIRD, vi, s1), s2);
        float f0 = fmaf(c4, 0.5f * vk0, s3a);
        float f1 = fmaf(c4, 0.5f * vk1, s3b);

#pragma unroll
        for (int l = 0; l < 8; ++l) {
            acc[l] = fmaf(f0, vv[l], acc[l]);
            acc[8 + l] = fmaf(f1, vv[l], acc[8 + l]);
        }
        s3a = fmaf(c3, vk0, s3a);
        s3b = fmaf(c3, vk1, s3b);
        s2 = fmaf(fmaf(0.5f, vi, s1), vj, s2);
        s1 += vi;
    }

    // ---- store segment signature to LDS ----
    {
        float* sg = sig[seg];
        if ((r & 31) == 0) sg[i] = s1;
        if ((r & 3) == 0) sg[8 + i * 8 + j] = s2;
        *(float2*)(&sg[72 + r * 2]) = make_float2(s3a, s3b);
        float* s4 = sg + 584 + r * 16;
        *(float4*)(s4) = make_float4(acc[0], acc[1], acc[2], acc[3]);
        *(float4*)(s4 + 4) = make_float4(acc[4], acc[5], acc[6], acc[7]);
        *(float4*)(s4 + 8) = make_float4(acc[8], acc[9], acc[10], acc[11]);
        *(float4*)(s4 + 12) = make_float4(acc[12], acc[13], acc[14], acc[15]);
    }
    __syncthreads();

    // ---- phase 2: 3 sequential Chen combines, result accumulates in sig[0] ----
    // level-4: each thread owns 4 elements: ijk4 = tid>>1 (0..511), l = l0..l0+3
    const int i4 = tid >> 7;
    const int j4 = (tid >> 4) & 7;
    const int k4 = (tid >> 1) & 7;
    const int l0 = (tid & 1) * 4;
    const int ijk4 = tid >> 1;

    for (int b = 1; b < NSEG; ++b) {
        const float* A = sig[0];
        const float* B = sig[b];

        // --- read + compute phase (no writes to sig[0]) ---
        float a3 = A[72 + ijk4];
        float a2 = A[8 + i4 * 8 + j4];
        float a1 = A[i4];
        float c4v[4];
#pragma unroll
        for (int m = 0; m < 4; ++m) {
            int l = l0 + m;
            float t = A[584 + ijk4 * 8 + l] + B[584 + ijk4 * 8 + l];
            t = fmaf(a3, B[l], t);
            t = fmaf(a2, B[8 + k4 * 8 + l], t);
            t = fmaf(a1, B[72 + j4 * 64 + k4 * 8 + l], t);
            c4v[m] = t;
        }
        float n3 = 0.f, n2 = 0.f, n1 = 0.f;
        if (tid < 512) { // wave-uniform
            int ii = tid >> 6, jj = (tid >> 3) & 7, kk = tid & 7;
            n3 = A[72 + tid] + B[72 + tid];
            n3 = fmaf(A[8 + ii * 8 + jj], B[kk], n3);
            n3 = fmaf(A[ii], B[8 + jj * 8 + kk], n3);
        }
        if (tid < 64) {
            int ii = tid >> 3, jj = tid & 7;
            n2 = A[8 + tid] + B[8 + tid] + A[ii] * B[jj];
        }
        if (tid < 8) n1 = A[tid] + B[tid];
        __syncthreads();   // all reads of sig[0] complete

        // --- write phase ---
        float* W = sig[0];
#pragma unroll
        for (int m = 0; m < 4; ++m) W[584 + ijk4 * 8 + l0 + m] = c4v[m];
        if (tid < 512) W[72 + tid] = n3;
        if (tid < 64) W[8 + tid] = n2;
        if (tid < 8) W[tid] = n1;
        __syncthreads();
    }

    // ---- coalesced write-out ----
    float* o = out + (size_t)n * OUT_PER;
    for (int idx = tid; idx < OUT_PER; idx += 1024) o[idx] = sig[0][idx];
}

extern "C" void kernel_launch(void* const* d_in, const int* in_sizes, int n_in,
                              void* d_out, int out_size, void* d_ws, size_t ws_size,
                              hipStream_t stream) {
    const float* path = (const float*)d_in[0];
    float* out = (float*)d_out;
    sig_kernel<<<N_SAMP, 1024, 0, stream>>>(path, out);
}